// Round 1
// baseline (44451.495 us; speedup 1.0000x reference)
//
#include <hip/hip_runtime.h>
#include <hip/hip_cooperative_groups.h>
#include <cstddef>

namespace cg = cooperative_groups;

#define B_ 128
#define S_ 512
#define I_ 1024
#define H_ 1024
#define G4_ 4096

// ---------------------------------------------------------------- zero init
__global__ __launch_bounds__(256) void k_zero(float* __restrict__ p, int n) {
  int i = blockIdx.x * 256 + threadIdx.x;
  if (i < n) p[i] = 0.0f;
}

// ---------------------------------------------------------------- big GEMM
// MODE 0: pre-GEMM. Chunk of Tc timesteps starting at t0.
//   C[tl*128 + b][4096] = x[b*512 + t0 + tl][1024] @ Wg_xpart + bias
//   grid = (32 n-tiles, T). Block by covers tl=by (all 128 b = tile rows).
// MODE 1: out-GEMM. C_out[(b*512+t0+by)] = hAllC[by*128+b][1024] @ Wout + bout
//   grid = (8, T).
// 128x128 tile, Ktile=32, 8x8 register tile, 256 threads.
template<int MODE>
__global__ __launch_bounds__(256) void k_gemm(
    const float* __restrict__ A,
    const float* __restrict__ W0, const float* __restrict__ W1,
    const float* __restrict__ W2, const float* __restrict__ W3,
    const float* __restrict__ bb0, const float* __restrict__ bb1,
    const float* __restrict__ bb2, const float* __restrict__ bb3,
    float* __restrict__ C, int t0)
{
  __shared__ float As[32 * 128];   // A tile, transposed [k][m]
  __shared__ float Bs[32 * 128];   // B tile, [k][n]
  const int tid = threadIdx.x;
  const int n0g = blockIdx.x * 128;
  const int by  = blockIdx.y;

  const float* Bmat;
  const float* bias;
  int g = 0, j0c = 0;
  if (MODE == 0) {
    g   = n0g >> 10;        // gate 0..3; 128 | 1024 so tile never straddles
    j0c = n0g & 1023;
    Bmat = ((g == 0) ? W0 : (g == 1) ? W1 : (g == 2) ? W2 : W3) + j0c;
    bias = ((g == 0) ? bb0 : (g == 1) ? bb1 : (g == 2) ? bb2 : bb3) + j0c;
  } else {
    Bmat = W0 + n0g;
    bias = bb0 + n0g;
  }

  const int tx = tid & 15, ty = tid >> 4;
  float acc[8][8];
#pragma unroll
  for (int i = 0; i < 8; ++i)
#pragma unroll
    for (int jq = 0; jq < 8; ++jq) acc[i][jq] = 0.0f;

  const int afr = tid & 7,  arow = tid >> 3;   // A staging: 8 float4 per k-row
  const int bnb = tid & 31, bkk  = tid >> 5;   // B staging

  for (int k0 = 0; k0 < 1024; k0 += 32) {
#pragma unroll
    for (int rr = 0; rr < 4; ++rr) {
      const int r = rr * 32 + arow;            // tile row = b (MODE0) / m (MODE1)
      size_t arowoff;
      if (MODE == 0) arowoff = ((size_t)r * 512 + (size_t)(t0 + by)) * 1024;
      else           arowoff = (size_t)(by * 128 + r) * 1024;
      const float4 v = *(const float4*)(A + arowoff + k0 + afr * 4);
      As[(afr * 4 + 0) * 128 + r] = v.x;
      As[(afr * 4 + 1) * 128 + r] = v.y;
      As[(afr * 4 + 2) * 128 + r] = v.z;
      As[(afr * 4 + 3) * 128 + r] = v.w;
    }
#pragma unroll
    for (int rr = 0; rr < 4; ++rr) {
      const int r = rr * 8 + bkk;
      *(float4*)(Bs + r * 128 + bnb * 4) =
          *(const float4*)(Bmat + (size_t)(k0 + r) * 1024 + bnb * 4);
    }
    __syncthreads();
#pragma unroll
    for (int kk = 0; kk < 32; ++kk) {
      const float4 a0 = *(const float4*)(As + kk * 128 + ty * 8);
      const float4 a1 = *(const float4*)(As + kk * 128 + ty * 8 + 4);
      const float4 w0 = *(const float4*)(Bs + kk * 128 + tx * 8);
      const float4 w1 = *(const float4*)(Bs + kk * 128 + tx * 8 + 4);
      const float av[8] = {a0.x, a0.y, a0.z, a0.w, a1.x, a1.y, a1.z, a1.w};
      const float wv[8] = {w0.x, w0.y, w0.z, w0.w, w1.x, w1.y, w1.z, w1.w};
#pragma unroll
      for (int i = 0; i < 8; ++i)
#pragma unroll
        for (int jq = 0; jq < 8; ++jq)
          acc[i][jq] = fmaf(av[i], wv[jq], acc[i][jq]);
    }
    __syncthreads();
  }

  float bv[8];
#pragma unroll
  for (int jq = 0; jq < 8; ++jq) bv[jq] = bias[tx * 8 + jq];

#pragma unroll
  for (int i = 0; i < 8; ++i) {
    const int r = ty * 8 + i;       // = b in both modes
    float* crow;
    if (MODE == 0) {
      crow = C + ((size_t)by * 128 + r) * G4_ + (size_t)g * 1024 + j0c + tx * 8;
    } else {
      crow = C + ((size_t)r * 512 + (size_t)(t0 + by)) * 1024 + n0g + tx * 8;
    }
    float4 o0, o1;
    o0.x = acc[i][0] + bv[0]; o0.y = acc[i][1] + bv[1];
    o0.z = acc[i][2] + bv[2]; o0.w = acc[i][3] + bv[3];
    o1.x = acc[i][4] + bv[4]; o1.y = acc[i][5] + bv[5];
    o1.z = acc[i][6] + bv[6]; o1.w = acc[i][7] + bv[7];
    *(float4*)crow       = o0;
    *(float4*)(crow + 4) = o1;
  }
}

// ---------------------------------------------------------------- persistent scan
// Cooperative kernel: 256 blocks x 256 threads, 1 block/CU (64 KB LDS).
// Block owns 4 hidden cols j0..j0+3 x 4 gates, all 128 b. W slice staged into
// LDS ONCE per chunk. c/n/m state lives in registers for the whole chunk:
// lane (w,kq,bq) owns (j = j0+kq, b = b0,b0+1). One grid.sync() per timestep.
__global__ __launch_bounds__(256) void k_scan(
    const float* __restrict__ Wf, const float* __restrict__ Wi,
    const float* __restrict__ Wc, const float* __restrict__ Wo,
    const float* __restrict__ preC,      // [T][128][4096]
    float* __restrict__ hA,              // hT0  [1024 j][128 b]
    float* __restrict__ hB,              // hT1
    float* __restrict__ cb, float* __restrict__ nb, float* __restrict__ mb,
    float* __restrict__ hAllC,           // [T*128][1024]
    int t0, int T)
{
  __shared__ float Wl[1024 * 16];        // 65536 B
  const int tid = threadIdx.x;
  const int j0  = blockIdx.x * 4;

  // ---- stage W h-part slice ONCE per chunk ----
#pragma unroll
  for (int r = 0; r < 16; ++r) {
    const int gk = r * 256 + tid;        // [0,4096)
    const int g = gk & 3, k = gk >> 2;
    const float* Wg = (g == 0) ? Wf : (g == 1) ? Wi : (g == 2) ? Wc : Wo;
    const float4 v = *(const float4*)(Wg + (size_t)(I_ + k) * H_ + j0);
    const int rot = (g + (k >> 8)) & 3;  // bank-phase rotation per K-range
    *(float4*)(&Wl[k * 16 + rot * 4]) = v;
  }
  __syncthreads();

  const int w    = tid >> 6;             // wave 0..3
  const int lane = tid & 63;
  const int bq   = lane & 15;
  const int kq   = lane >> 4;            // K-split 0..3
  const int b0   = w * 32 + bq * 2;
  const int jown = j0 + kq;              // this lane's owned hidden col
  const int sOwn = jown * 128 + b0;

  // ---- state in registers for the whole chunk ----
  float c_r[2], n_r[2], m_r[2];
  c_r[0] = cb[sOwn]; c_r[1] = cb[sOwn + 1];
  n_r[0] = nb[sOwn]; n_r[1] = nb[sOwn + 1];
  m_r[0] = mb[sOwn]; m_r[1] = mb[sOwn + 1];

  const int r0 = ((0 + kq) & 3) * 4;     // per-thread rotated g offsets
  const int r1 = ((1 + kq) & 3) * 4;
  const int r2 = ((2 + kq) & 3) * 4;
  const int r3 = ((3 + kq) & 3) * 4;
  const int kbase = kq * 256;

  cg::grid_group grid = cg::this_grid();

  for (int tl = 0; tl < T; ++tl) {
    const int tg = t0 + tl;
    const float* __restrict__ hin = (tg & 1) ? hB : hA;
    float* __restrict__ hout      = (tg & 1) ? hA : hB;

    // ---- prefetch pre-gate values for this lane's cells (hidden under GEMM)
    const float* pre_t = preC + (size_t)tl * (128 * 4096);
    float pr0[2], pr1[2], pr2[2], pr3[2];
#pragma unroll
    for (int ib = 0; ib < 2; ++ib) {
      const float* pb = pre_t + (size_t)(b0 + ib) * 4096 + jown;
      pr0[ib] = pb[0];
      pr1[ib] = pb[1024];
      pr2[ib] = pb[2048];
      pr3[ib] = pb[3072];
    }

    // ---- GEMM: h(t-1) @ W_hpart for 16 gc columns, K-split by kq ----
    float acc[2][16];
#pragma unroll
    for (int ib = 0; ib < 2; ++ib)
#pragma unroll
      for (int c = 0; c < 16; ++c) acc[ib][c] = 0.0f;

#pragma unroll 2
    for (int ki = 0; ki < 256; ++ki) {
      const int k = kbase + ki;
      const float2 h2 = *(const float2*)(hin + (size_t)k * 128 + b0);
      const float4 w0 = *(const float4*)(&Wl[k * 16 + r0]);   // gate f, jj 0..3
      const float4 w1 = *(const float4*)(&Wl[k * 16 + r1]);   // gate i
      const float4 w2 = *(const float4*)(&Wl[k * 16 + r2]);   // gate c
      const float4 w3 = *(const float4*)(&Wl[k * 16 + r3]);   // gate o
      const float wv[16] = {w0.x, w0.y, w0.z, w0.w, w1.x, w1.y, w1.z, w1.w,
                            w2.x, w2.y, w2.z, w2.w, w3.x, w3.y, w3.z, w3.w};
#pragma unroll
      for (int c = 0; c < 16; ++c) {
        acc[0][c] = fmaf(h2.x, wv[c], acc[0][c]);
        acc[1][c] = fmaf(h2.y, wv[c], acc[1][c]);
      }
    }

    // ---- shuffle reduce over kq: every lane ends with full sums ----
#pragma unroll
    for (int ib = 0; ib < 2; ++ib)
#pragma unroll
      for (int c = 0; c < 16; ++c) {
        float v = acc[ib][c];
        v += __shfl_xor(v, 16);
        v += __shfl_xor(v, 32);
        acc[ib][c] = v;
      }

    // ---- epilogue: lane handles jj = kq for its b-pair.
    // NOTE: select acc columns with compile-time indices (4-way branch) —
    // runtime-indexed register arrays would spill to scratch.
    float hn[2];
#pragma unroll
    for (int ib = 0; ib < 2; ++ib) {
      float a0, a1, a2, a3;
      if      (kq == 0) { a0 = acc[ib][0]; a1 = acc[ib][4]; a2 = acc[ib][8];  a3 = acc[ib][12]; }
      else if (kq == 1) { a0 = acc[ib][1]; a1 = acc[ib][5]; a2 = acc[ib][9];  a3 = acc[ib][13]; }
      else if (kq == 2) { a0 = acc[ib][2]; a1 = acc[ib][6]; a2 = acc[ib][10]; a3 = acc[ib][14]; }
      else              { a0 = acc[ib][3]; a1 = acc[ib][7]; a2 = acc[ib][11]; a3 = acc[ib][15]; }

      const float f_log = a0 + pr0[ib];
      const float i_log = a1 + pr1[ib];
      const float c_log = a2 + pr2[ib];
      const float o_log = a3 + pr3[ib];

      const float m_new = fmaxf(f_log + m_r[ib], i_log);
      const float i_t   = expf(i_log - m_new);
      const float f_t   = expf(f_log + m_r[ib] - m_new);
      const float c_hat = tanhf(c_log);
      const float o_t   = 1.0f / (1.0f + expf(-o_log));
      const float c_new = f_t * c_r[ib] + i_t * c_hat;
      const float n_new = f_t * n_r[ib] + i_t;
      hn[ib] = o_t * (c_new / (n_new + 1e-8f));
      c_r[ib] = c_new; n_r[ib] = n_new; m_r[ib] = m_new;
    }

    *(float2*)(hout + sOwn) = make_float2(hn[0], hn[1]);
    hAllC[((size_t)tl * 128 + b0    ) * 1024 + jown] = hn[0];
    hAllC[((size_t)tl * 128 + b0 + 1) * 1024 + jown] = hn[1];

    grid.sync();   // h(t) visible device-wide before step t+1 reads it
  }

  // ---- write back state at chunk boundary ----
  cb[sOwn] = c_r[0]; cb[sOwn + 1] = c_r[1];
  nb[sOwn] = n_r[0]; nb[sOwn + 1] = n_r[1];
  mb[sOwn] = m_r[0]; mb[sOwn + 1] = m_r[1];
}

// ---------------------------------------------------------------- scan step (fallback)
// Per-step launch variant, kept as the known-good path if cooperative launch
// is unavailable. Identical math/layout to the previous session's kernel.
__global__ __launch_bounds__(256) void k_step(
    const float* __restrict__ Wf, const float* __restrict__ Wi,
    const float* __restrict__ Wc, const float* __restrict__ Wo,
    const float* __restrict__ preC,      // [Tc][128][4096]
    const float* __restrict__ hT_in,     // [1024 j][128 b]
    float* __restrict__ hT_out,
    float* __restrict__ cb, float* __restrict__ nb, float* __restrict__ mb,
    float* __restrict__ hAllC,           // [Tc*128][1024]
    int t_local)
{
  __shared__ float Wl[1024 * 16];        // 65536 B
  const int tid = threadIdx.x;
  const int j0  = blockIdx.x * 4;

#pragma unroll
  for (int r = 0; r < 16; ++r) {
    const int gk = r * 256 + tid;
    const int g = gk & 3, k = gk >> 2;
    const float* Wg = (g == 0) ? Wf : (g == 1) ? Wi : (g == 2) ? Wc : Wo;
    const float4 v = *(const float4*)(Wg + (size_t)(I_ + k) * H_ + j0);
    const int rot = (g + (k >> 8)) & 3;
    *(float4*)(&Wl[k * 16 + rot * 4]) = v;
  }
  __syncthreads();

  const int w    = tid >> 6;
  const int lane = tid & 63;
  const int bq   = lane & 15;
  const int kq   = lane >> 4;
  const int b0   = w * 32 + bq * 2;

  float acc[2][16];
#pragma unroll
  for (int ib = 0; ib < 2; ++ib)
#pragma unroll
    for (int c = 0; c < 16; ++c) acc[ib][c] = 0.0f;

  const int r0 = ((0 + kq) & 3) * 4;
  const int r1 = ((1 + kq) & 3) * 4;
  const int r2 = ((2 + kq) & 3) * 4;
  const int r3 = ((3 + kq) & 3) * 4;
  const int kbase = kq * 256;

#pragma unroll 2
  for (int ki = 0; ki < 256; ++ki) {
    const int k = kbase + ki;
    const float2 h2 = *(const float2*)(hT_in + (size_t)k * 128 + b0);
    const float4 w0 = *(const float4*)(&Wl[k * 16 + r0]);
    const float4 w1 = *(const float4*)(&Wl[k * 16 + r1]);
    const float4 w2 = *(const float4*)(&Wl[k * 16 + r2]);
    const float4 w3 = *(const float4*)(&Wl[k * 16 + r3]);
    const float wv[16] = {w0.x, w0.y, w0.z, w0.w, w1.x, w1.y, w1.z, w1.w,
                          w2.x, w2.y, w2.z, w2.w, w3.x, w3.y, w3.z, w3.w};
#pragma unroll
    for (int c = 0; c < 16; ++c) {
      acc[0][c] = fmaf(h2.x, wv[c], acc[0][c]);
      acc[1][c] = fmaf(h2.y, wv[c], acc[1][c]);
    }
  }
  __syncthreads();

  const float* pre_t = preC + (size_t)t_local * (128 * 4096);
#pragma unroll
  for (int r = 0; r < 2; ++r) {
    const int id = r * 256 + tid;
    const int g = id & 3, b = id >> 2;
    const float4 v = *(const float4*)(pre_t + (size_t)b * 4096 + g * 1024 + j0);
    *(float4*)(&Wl[b * 16 + g * 4]) = v;
  }

#pragma unroll
  for (int ib = 0; ib < 2; ++ib)
#pragma unroll
    for (int c = 0; c < 16; ++c) {
      float v = acc[ib][c];
      v += __shfl_xor(v, 16);
      v += __shfl_xor(v, 32);
      acc[ib][c] = v;
    }
  __syncthreads();

  if (kq == 0) {
#pragma unroll
    for (int ib = 0; ib < 2; ++ib) {
      const int b = b0 + ib;
#pragma unroll
      for (int jj = 0; jj < 4; ++jj) {
        const int j = j0 + jj;
        const float f_log = acc[ib][0  + jj] + Wl[b * 16 + 0  + jj];
        const float i_log = acc[ib][4  + jj] + Wl[b * 16 + 4  + jj];
        const float c_log = acc[ib][8  + jj] + Wl[b * 16 + 8  + jj];
        const float o_log = acc[ib][12 + jj] + Wl[b * 16 + 12 + jj];

        const int sIdx = j * 128 + b;
        const float m_old = mb[sIdx];
        const float c_old = cb[sIdx];
        const float n_old = nb[sIdx];

        const float m_new = fmaxf(f_log + m_old, i_log);
        const float i_t   = expf(i_log - m_new);
        const float f_t   = expf(f_log + m_old - m_new);
        const float c_hat = tanhf(c_log);
        const float o_t   = 1.0f / (1.0f + expf(-o_log));
        const float c_new = f_t * c_old + i_t * c_hat;
        const float n_new = f_t * n_old + i_t;
        const float h_new = o_t * (c_new / (n_new + 1e-8f));

        cb[sIdx] = c_new;
        nb[sIdx] = n_new;
        mb[sIdx] = m_new;
        hT_out[sIdx] = h_new;
        hAllC[((size_t)t_local * 128 + b) * 1024 + j] = h_new;
      }
    }
  }
}

// ---------------------------------------------------------------- final state tail
__global__ __launch_bounds__(256) void k_tail(
    const float* __restrict__ hT, const float* __restrict__ cbp,
    const float* __restrict__ nbp, const float* __restrict__ mbp,
    float* __restrict__ dst)
{
  const int gid = blockIdx.x * 256 + threadIdx.x;   // [0, 4*131072)
  const int q = gid >> 17, rem = gid & 131071;
  const int b = rem >> 10, j = rem & 1023;
  const float* src = (q == 0) ? hT : (q == 1) ? cbp : (q == 2) ? nbp : mbp;
  dst[gid] = src[j * B_ + b];
}

// ---------------------------------------------------------------- launch
extern "C" void kernel_launch(void* const* d_in, const int* in_sizes, int n_in,
                              void* d_out, int out_size, void* d_ws, size_t ws_size,
                              hipStream_t stream) {
  const float* Wf   = (const float*)d_in[1];
  const float* bfv  = (const float*)d_in[2];
  const float* Wi   = (const float*)d_in[3];
  const float* biv  = (const float*)d_in[4];
  const float* Wc   = (const float*)d_in[5];
  const float* bcv  = (const float*)d_in[6];
  const float* Wo   = (const float*)d_in[7];
  const float* bov  = (const float*)d_in[8];
  const float* Wout = (const float*)d_in[9];
  const float* bout = (const float*)d_in[10];
  const float* x    = (const float*)d_in[0];
  float* out = (float*)d_out;

  // workspace layout: states first, then chunk buffers sized to fit ws_size
  float* hT0 = (float*)d_ws;
  float* hT1 = hT0 + 131072;
  float* cb  = hT0 + 2 * 131072;
  float* nb  = hT0 + 3 * 131072;
  float* mb  = hT0 + 4 * 131072;
  float* chunk0 = hT0 + 5 * 131072;

  const size_t stateBytes = (size_t)5 * 131072 * sizeof(float);
  const size_t perT = ((size_t)128 * 4096 + (size_t)128 * 1024) * sizeof(float); // 2.5 MiB/step
  const size_t avail = (ws_size > stateBytes) ? (ws_size - stateBytes) : 0;
  int Tc = (int)(avail / perT);
  if (Tc > S_) Tc = S_;
  if (Tc < 1)  Tc = 1;

  float* preC  = chunk0;                          // [Tc][128][4096]
  float* hAllC = preC + (size_t)Tc * 128 * 4096;  // [Tc*128][1024]

  // zero h, c, n, m (ws is poisoned 0xAA every call)
  k_zero<<<2560, 256, 0, stream>>>(hT0, 5 * 131072);

  static int coop_ok = -1;   // -1 unknown, 1 works, 0 fall back to per-step

  for (int t0 = 0; t0 < S_; t0 += Tc) {
    const int T = (S_ - t0 < Tc) ? (S_ - t0) : Tc;

    // pre-gates for this chunk: x-part of all 4 gate GEMMs + bias
    k_gemm<0><<<dim3(32, T), 256, 0, stream>>>(x, Wf, Wi, Wc, Wo,
                                               bfv, biv, bcv, bov, preC, t0);

    bool scanned = false;
    if (coop_ok != 0) {
      int t0v = t0, Tv = T;
      void* args[] = {(void*)&Wf, (void*)&Wi, (void*)&Wc, (void*)&Wo,
                      (void*)&preC, (void*)&hT0, (void*)&hT1,
                      (void*)&cb, (void*)&nb, (void*)&mb, (void*)&hAllC,
                      (void*)&t0v, (void*)&Tv};
      hipError_t e = hipLaunchCooperativeKernel(
          reinterpret_cast<void*>(k_scan), dim3(256), dim3(256), args, 0, stream);
      if (e == hipSuccess) { coop_ok = 1; scanned = true; }
      else                 { coop_ok = 0; }
    }
    if (!scanned) {
      // fallback: sequential per-step launches (previous known-good path)
      for (int tl = 0; tl < T; ++tl) {
        const int tg = t0 + tl;
        const float* hin = (tg & 1) ? hT1 : hT0;
        float* hout      = (tg & 1) ? hT0 : hT1;
        k_step<<<256, 256, 0, stream>>>(Wf, Wi, Wc, Wo, preC, hin, hout,
                                        cb, nb, mb, hAllC, tl);
      }
    }

    // outputs for this chunk: hAllC @ Wout + bout
    k_gemm<1><<<dim3(8, T), 256, 0, stream>>>(hAllC, Wout, Wout, Wout, Wout,
                                              bout, bout, bout, bout, out, t0);
  }

  // final h, c, n, m (h ends in hT0 after 512 steps)
  k_tail<<<2048, 256, 0, stream>>>(hT0, cb, nb, mb, out + (size_t)B_ * S_ * H_);
}

// Round 5
// 16592.480 us; speedup vs baseline: 2.6790x; 2.6790x over previous
//
#include <hip/hip_runtime.h>
#include <cstddef>

#define B_ 128
#define S_ 512
#define I_ 1024
#define H_ 1024
#define G4_ 4096

typedef __attribute__((ext_vector_type(8))) short bf16x8;   // 8 bf16 = 4 VGPR
typedef __attribute__((ext_vector_type(4))) float f32x4;
typedef unsigned short u16;
typedef unsigned int   u32;

// round-to-nearest bf16 (bit trick; half-up, bias negligible)
__device__ inline u16 bf16_rn(float x) {
  return (u16)((__float_as_uint(x) + 0x8000u) >> 16);
}
// rounded hi + exact residual (residual exactly representable: hi within 2^-8 of x)
__device__ inline u16 bf16_hi_rem(float x, float& rem) {
  const u32 hb = (__float_as_uint(x) + 0x8000u) & 0xFFFF0000u;
  rem = x - __uint_as_float(hb);
  return (u16)(hb >> 16);
}

// ---------------------------------------------------------------- zero init
__global__ __launch_bounds__(256) void k_zero(float* __restrict__ p, int n) {
  int i = blockIdx.x * 256 + threadIdx.x;
  if (i < n) p[i] = 0.0f;
}

// ---------------------------------------------------------------- W transpose (scan image, fp32, h-part)
// WT[j4 block 256][slot 4096][4], slot = ki*64 + g*16 + kq, k = kq*64 + ki.
__global__ __launch_bounds__(256) void k_wt(
    const float* __restrict__ Wf, const float* __restrict__ Wi,
    const float* __restrict__ Wc, const float* __restrict__ Wo,
    float* __restrict__ WT)
{
  const int gid = blockIdx.x * 256 + threadIdx.x;   // [0, 1048576)
  const int j4 = gid >> 12;
  const int s  = gid & 4095;
  const int ki = s >> 6, g = (s >> 4) & 3, kq = s & 15;
  const int k  = kq * 64 + ki;
  const float* Wg = (g == 0) ? Wf : (g == 1) ? Wi : (g == 2) ? Wc : Wo;
  const float4 v = *(const float4*)(Wg + (size_t)(I_ + k) * H_ + j4 * 4);
  *(float4*)(WT + (size_t)gid * 4) = v;
}

// ---------------------------------------------------------------- W split+transpose (GEMM B operands)
// z<4: Wxt[n = z*1024 + j][k] = Wg[k][j] (x-part rows 0..1023), hi/lo bf16.
// z==4: Wot[n][k] = Wout[k][n], hi/lo bf16.
// grid (16 k-tiles, 16 j-tiles, 5), 64x64 LDS tile transpose.
__global__ __launch_bounds__(256) void k_tr(
    const float* __restrict__ Wf, const float* __restrict__ Wi,
    const float* __restrict__ Wc, const float* __restrict__ Wo,
    const float* __restrict__ Wout,
    u16* __restrict__ Wxt_hi, u16* __restrict__ Wxt_lo,
    u16* __restrict__ Wot_hi, u16* __restrict__ Wot_lo)
{
  __shared__ float T_[64][65];
  const int kt = blockIdx.x, jt = blockIdx.y, z = blockIdx.z;
  const float* src = (z == 0) ? Wf : (z == 1) ? Wi : (z == 2) ? Wc
                     : (z == 3) ? Wo : Wout;
  u16* dh = (z < 4) ? Wxt_hi : Wot_hi;
  u16* dl = (z < 4) ? Wxt_lo : Wot_lo;
  const int nbase = (z < 4) ? (z * 1024 + jt * 64) : (jt * 64);
  const int tid = threadIdx.x;

#pragma unroll
  for (int it = 0; it < 4; ++it) {
    const int idx = it * 1024 + tid * 4;      // float4 granule
    const int a = idx >> 6, c = idx & 63;     // a = k-row, c = j-col
    const float4 v = *(const float4*)(src + (size_t)(kt * 64 + a) * 1024 + jt * 64 + c);
    T_[a][c] = v.x; T_[a][c + 1] = v.y; T_[a][c + 2] = v.z; T_[a][c + 3] = v.w;
  }
  __syncthreads();
#pragma unroll
  for (int it = 0; it < 16; ++it) {
    const int idx = it * 256 + tid;
    const int j = idx >> 6, k = idx & 63;     // lanes -> consecutive k (coalesced)
    const float xv = T_[k][j];
    float rem;
    const u16 hi = bf16_hi_rem(xv, rem);
    const u16 lo = bf16_rn(rem);
    const size_t o = (size_t)(nbase + j) * 1024 + kt * 64 + k;
    dh[o] = hi; dl[o] = lo;
  }
}

// ---------------------------------------------------------------- gate-bias concat
__global__ __launch_bounds__(256) void k_bias(
    const float* __restrict__ b0, const float* __restrict__ b1,
    const float* __restrict__ b2, const float* __restrict__ b3,
    float* __restrict__ b4)
{
  const int i = blockIdx.x * 256 + threadIdx.x;     // [0,4096)
  const int g = i >> 10;
  const float* s = (g == 0) ? b0 : (g == 1) ? b1 : (g == 2) ? b2 : b3;
  b4[i] = s[i & 1023];
}

// ---------------------------------------------------------------- x split (per chunk)
// xs_hi/lo[(tl*128 + b)][k] = split(x[b][t0+tl][k]). grid (64, T).
__global__ __launch_bounds__(256) void k_xsplit(
    const float* __restrict__ x, u16* __restrict__ xh, u16* __restrict__ xl, int t0)
{
  const int id = blockIdx.x * 256 + threadIdx.x;    // [0, 16384)
  const int tl = blockIdx.y;
  const int b  = id >> 7;
  const int k8 = (id & 127) << 3;
  const float* s = x + ((size_t)b * 512 + (size_t)(t0 + tl)) * 1024 + k8;
  const float4 v0 = *(const float4*)(s);
  const float4 v1 = *(const float4*)(s + 4);
  const float vs[8] = {v0.x, v0.y, v0.z, v0.w, v1.x, v1.y, v1.z, v1.w};
  u32 hw[4], lw[4];
#pragma unroll
  for (int p = 0; p < 4; ++p) {
    float r0, r1;
    const u16 h0 = bf16_hi_rem(vs[2 * p], r0);
    const u16 h1 = bf16_hi_rem(vs[2 * p + 1], r1);
    hw[p] = (u32)h0 | ((u32)h1 << 16);
    lw[p] = (u32)bf16_rn(r0) | ((u32)bf16_rn(r1) << 16);
  }
  const size_t o = ((size_t)tl * 128 + b) * 1024 + k8;
  *(uint4*)(xh + o) = make_uint4(hw[0], hw[1], hw[2], hw[3]);
  *(uint4*)(xl + o) = make_uint4(lw[0], lw[1], lw[2], lw[3]);
}

// ---------------------------------------------------------------- MFMA GEMM
// C[M=T*128][N] = A[M][1024] @ B[N][1024]^T + bias, A/B pre-split bf16 (n-major, k-contig).
// MODE 0 (pre-gates): N=4096, bf16x3 split (AhiBhi + AhiBlo + AloBhi), C=preC[(tl*128+b)][4096].
// MODE 1 (out-proj):  N=1024, single product, C=out[b][t0+tl][1024].
// 128x128 tile, BK=32, 256 thr = 4 waves (2x2), per wave 4x4 frags of 16x16x32.
// LDS: [row][4 slots of 8 bf16], slot XOR-swizzled: sl = h ^ ((row>>1)&3) -> 2-way banks (free).
template<int MODE>
__global__ __launch_bounds__(256) void k_gemm_mfma(
    const u16* __restrict__ Ahg, const u16* __restrict__ Alg,
    const u16* __restrict__ Bhg, const u16* __restrict__ Blg,
    const float* __restrict__ bias,
    float* __restrict__ C, int t0)
{
  __shared__ u16 Ah[4096], Al[4096], Bh[4096], Bl[4096];
  const int tid = threadIdx.x;
  const int n0  = blockIdx.x * 128;
  const int by  = blockIdx.y;                 // = tl (one timestep per M-tile)

  const int w = tid >> 6, lane = tid & 63;
  const int wm = w >> 1, wn = w & 1;
  const int lr = lane & 15, lh = lane >> 4;   // frag row/col, k-half

  f32x4 acc[4][4];
#pragma unroll
  for (int mi = 0; mi < 4; ++mi)
#pragma unroll
    for (int ni = 0; ni < 4; ++ni) acc[mi][ni] = (f32x4){0.f, 0.f, 0.f, 0.f};

  // staging: thread covers 2 chunks of 16B; row = tid>>1, slots {0,1} or {2,3}
  const int srow  = tid >> 1;
  const int sb    = (tid & 1) * 2;
  const int swz   = (srow >> 1) & 3;
  const int l0 = srow * 32 + ((sb ^ swz) << 3);
  const int l1 = srow * 32 + (((sb + 1) ^ swz) << 3);
  const size_t ga = (size_t)(by * 128 + srow) * 1024 + (sb << 3);
  const size_t gb = (size_t)(n0 + srow) * 1024 + (sb << 3);

  // frag LDS offsets are K-invariant: precompute
  int aoff[4], boff[4];
#pragma unroll
  for (int mi = 0; mi < 4; ++mi) {
    const int R = wm * 64 + mi * 16 + lr;
    aoff[mi] = R * 32 + ((lh ^ ((R >> 1) & 3)) << 3);
  }
#pragma unroll
  for (int ni = 0; ni < 4; ++ni) {
    const int Rn = wn * 64 + ni * 16 + lr;
    boff[ni] = Rn * 32 + ((lh ^ ((Rn >> 1) & 3)) << 3);
  }

  for (int k0 = 0; k0 < 1024; k0 += 32) {
    const uint4 vah0 = *(const uint4*)(Ahg + ga + k0);
    const uint4 vah1 = *(const uint4*)(Ahg + ga + k0 + 8);
    const uint4 vbh0 = *(const uint4*)(Bhg + gb + k0);
    const uint4 vbh1 = *(const uint4*)(Bhg + gb + k0 + 8);
    uint4 val0, val1, vbl0, vbl1;
    if (MODE == 0) {
      val0 = *(const uint4*)(Alg + ga + k0);
      val1 = *(const uint4*)(Alg + ga + k0 + 8);
      vbl0 = *(const uint4*)(Blg + gb + k0);
      vbl1 = *(const uint4*)(Blg + gb + k0 + 8);
    }
    __syncthreads();                      // waves done reading previous tile
    *(uint4*)(Ah + l0) = vah0; *(uint4*)(Ah + l1) = vah1;
    *(uint4*)(Bh + l0) = vbh0; *(uint4*)(Bh + l1) = vbh1;
    if (MODE == 0) {
      *(uint4*)(Al + l0) = val0; *(uint4*)(Al + l1) = val1;
      *(uint4*)(Bl + l0) = vbl0; *(uint4*)(Bl + l1) = vbl1;
    }
    __syncthreads();                      // tile visible

    bf16x8 ahf[4], alf[4];
#pragma unroll
    for (int mi = 0; mi < 4; ++mi) {
      ahf[mi] = *(const bf16x8*)(&Ah[aoff[mi]]);
      if (MODE == 0) alf[mi] = *(const bf16x8*)(&Al[aoff[mi]]);
    }
#pragma unroll
    for (int ni = 0; ni < 4; ++ni) {
      const bf16x8 bhf = *(const bf16x8*)(&Bh[boff[ni]]);
      bf16x8 blf;
      if (MODE == 0) blf = *(const bf16x8*)(&Bl[boff[ni]]);
#pragma unroll
      for (int mi = 0; mi < 4; ++mi) {
        acc[mi][ni] = __builtin_amdgcn_mfma_f32_16x16x32_bf16(ahf[mi], bhf, acc[mi][ni], 0, 0, 0);
        if (MODE == 0) {
          acc[mi][ni] = __builtin_amdgcn_mfma_f32_16x16x32_bf16(ahf[mi], blf, acc[mi][ni], 0, 0, 0);
          acc[mi][ni] = __builtin_amdgcn_mfma_f32_16x16x32_bf16(alf[mi], bhf, acc[mi][ni], 0, 0, 0);
        }
      }
    }
  }

  // epilogue: D row = (lane>>4)*4 + q, col = lane&15 (m89-verified layout)
#pragma unroll
  for (int ni = 0; ni < 4; ++ni) {
    const int n = n0 + wn * 64 + ni * 16 + lr;
    const float bv = bias[n];
#pragma unroll
    for (int mi = 0; mi < 4; ++mi) {
      const int rb = wm * 64 + mi * 16 + lh * 4;
#pragma unroll
      for (int q = 0; q < 4; ++q) {
        const int r = rb + q;
        const float v = acc[mi][ni][q] + bv;
        if (MODE == 0) C[((size_t)by * 128 + r) * 4096 + n] = v;
        else           C[((size_t)r * 512 + (size_t)(t0 + by)) * 1024 + n] = v;
      }
    }
  }
}

// ---------------------------------------------------------------- scan step
// (verified round-2 kernel; only change: h output also stored as rounded bf16
// for the single-product out-GEMM. Recurrence h stays fp32.)
__global__ __launch_bounds__(512) void k_step2(
    const float* __restrict__ WT,
    const float* __restrict__ preC,      // [Tc][128][4096]
    const float* __restrict__ hT_in,     // [1024 j][128 b]
    float* __restrict__ hT_out,
    float* __restrict__ cb, float* __restrict__ nb, float* __restrict__ mb,
    u16* __restrict__ hAllH,             // [Tc*128][1024] bf16
    int t_local)
{
  __shared__ float Wl[16384];            // 65536 B, [ki][g][kq][jj]
  const int tid = threadIdx.x;
  const int bid = blockIdx.x;
  const int j0  = bid * 4;

  const int w    = tid >> 6;             // wave 0..7
  const int lane = tid & 63;
  const int kq   = lane & 15;            // K-split 0..15 (64 k each)
  const int bq   = lane >> 4;            // b-quad 0..3
  const int b0   = w * 16 + bq * 4;

  const int jj = kq & 3, ib = kq >> 2;
  const int bc = b0 + ib;
  const int jc = j0 + jj;
  const int sIdx = jc * 128 + bc;

  const float* pre_t = preC + (size_t)t_local * (128 * 4096) + (size_t)bc * 4096 + jc;
  const float pf = pre_t[0];
  const float pi = pre_t[1024];
  const float pc = pre_t[2048];
  const float po = pre_t[3072];
  const float m_old = mb[sIdx];
  const float c_old = cb[sIdx];
  const float n_old = nb[sIdx];

  const float* wt = WT + (size_t)bid * 16384;
#pragma unroll
  for (int r = 0; r < 8; ++r) {
    const int idx = r * 512 + tid;
    *(float4*)(&Wl[idx * 4]) = *(const float4*)(wt + (size_t)idx * 4);
  }
  __syncthreads();

  float acc[4][16];
#pragma unroll
  for (int i = 0; i < 4; ++i)
#pragma unroll
    for (int c = 0; c < 16; ++c) acc[i][c] = 0.0f;

  const float* hbase = hT_in + (size_t)kq * (64 * 128) + b0;
  const float* wb0   = &Wl[kq * 4];

  float4 h_c = *(const float4*)(hbase);
  float4 h_n = *(const float4*)(hbase + 128);
  float4 wA = *(const float4*)(wb0 + 0);
  float4 wB = *(const float4*)(wb0 + 64);
  float4 wC = *(const float4*)(wb0 + 128);
  float4 wD = *(const float4*)(wb0 + 192);

#pragma unroll 2
  for (int ki = 0; ki < 64; ++ki) {
    const int kin = (ki + 1) & 63;
    const int ki2 = (ki + 2) & 63;
    const float4 h_p = *(const float4*)(hbase + ki2 * 128);
    const float4 nA = *(const float4*)(wb0 + kin * 256 + 0);
    const float4 nB = *(const float4*)(wb0 + kin * 256 + 64);
    const float4 nC = *(const float4*)(wb0 + kin * 256 + 128);
    const float4 nD = *(const float4*)(wb0 + kin * 256 + 192);
    const float av[4] = {h_c.x, h_c.y, h_c.z, h_c.w};
    const float wv[16] = {wA.x, wA.y, wA.z, wA.w, wB.x, wB.y, wB.z, wB.w,
                          wC.x, wC.y, wC.z, wC.w, wD.x, wD.y, wD.z, wD.w};
#pragma unroll
    for (int i = 0; i < 4; ++i)
#pragma unroll
      for (int c = 0; c < 16; ++c)
        acc[i][c] = fmaf(av[i], wv[c], acc[i][c]);
    h_c = h_n; h_n = h_p;
    wA = nA; wB = nB; wC = nC; wD = nD;
  }

#pragma unroll
  for (int i = 0; i < 4; ++i)
#pragma unroll
    for (int c = 0; c < 16; ++c) {
      float v = acc[i][c];
      v += __shfl_xor(v, 1);
      v += __shfl_xor(v, 2);
      v += __shfl_xor(v, 4);
      v += __shfl_xor(v, 8);
      acc[i][c] = v;
    }

  float f_in, i_in, cc_in, o_in;
#define PICK_CASE(KQ) \
  case KQ: f_in = acc[(KQ) >> 2][(KQ) & 3];        \
           i_in = acc[(KQ) >> 2][4 + ((KQ) & 3)];  \
           cc_in = acc[(KQ) >> 2][8 + ((KQ) & 3)]; \
           o_in = acc[(KQ) >> 2][12 + ((KQ) & 3)]; break;
  switch (kq) {
    PICK_CASE(0)  PICK_CASE(1)  PICK_CASE(2)  PICK_CASE(3)
    PICK_CASE(4)  PICK_CASE(5)  PICK_CASE(6)  PICK_CASE(7)
    PICK_CASE(8)  PICK_CASE(9)  PICK_CASE(10) PICK_CASE(11)
    PICK_CASE(12) PICK_CASE(13) PICK_CASE(14) PICK_CASE(15)
    default: f_in = i_in = cc_in = o_in = 0.0f; break;
  }
#undef PICK_CASE

  const float f_log = f_in + pf;
  const float i_log = i_in + pi;
  const float c_log = cc_in + pc;
  const float o_log = o_in + po;

  const float m_new = fmaxf(f_log + m_old, i_log);
  const float i_t   = expf(i_log - m_new);
  const float f_t   = expf(f_log + m_old - m_new);
  const float c_hat = tanhf(c_log);
  const float o_t   = 1.0f / (1.0f + expf(-o_log));
  const float c_new = f_t * c_old + i_t * c_hat;
  const float n_new = f_t * n_old + i_t;
  const float h_new = o_t * (c_new / (n_new + 1e-8f));

  cb[sIdx] = c_new;
  nb[sIdx] = n_new;
  mb[sIdx] = m_new;
  hT_out[sIdx] = h_new;                                         // [j][b] fp32
  hAllH[((size_t)t_local * 128 + bc) * 1024 + jc] = bf16_rn(h_new);
}

// ---------------------------------------------------------------- final state tail
__global__ __launch_bounds__(256) void k_tail(
    const float* __restrict__ hT, const float* __restrict__ cbp,
    const float* __restrict__ nbp, const float* __restrict__ mbp,
    float* __restrict__ dst)
{
  const int gid = blockIdx.x * 256 + threadIdx.x;   // [0, 4*131072)
  const int q = gid >> 17, rem = gid & 131071;
  const int b = rem >> 10, j = rem & 1023;
  const float* src = (q == 0) ? hT : (q == 1) ? cbp : (q == 2) ? nbp : mbp;
  dst[gid] = src[j * B_ + b];
}

// ---------------------------------------------------------------- launch
extern "C" void kernel_launch(void* const* d_in, const int* in_sizes, int n_in,
                              void* d_out, int out_size, void* d_ws, size_t ws_size,
                              hipStream_t stream) {
  const float* x    = (const float*)d_in[0];
  const float* Wf   = (const float*)d_in[1];
  const float* bfv  = (const float*)d_in[2];
  const float* Wi   = (const float*)d_in[3];
  const float* biv  = (const float*)d_in[4];
  const float* Wc   = (const float*)d_in[5];
  const float* bcv  = (const float*)d_in[6];
  const float* Wo   = (const float*)d_in[7];
  const float* bov  = (const float*)d_in[8];
  const float* Wout = (const float*)d_in[9];
  const float* bout = (const float*)d_in[10];
  float* out = (float*)d_out;

  // workspace: states | WT 16MB | Wxt hi/lo 16MB | Wot hi/lo 4MB | bias | chunks
  float* hT0 = (float*)d_ws;
  float* hT1 = hT0 + 131072;
  float* cb  = hT0 + 2 * 131072;
  float* nb  = hT0 + 3 * 131072;
  float* mb  = hT0 + 4 * 131072;
  float* WT  = hT0 + 5 * 131072;
  u16* Wxt_hi = (u16*)(WT + 4194304);
  u16* Wxt_lo = Wxt_hi + 4194304;
  u16* Wot_hi = Wxt_lo + 4194304;
  u16* Wot_lo = Wot_hi + 1048576;
  float* bias4  = (float*)(Wot_lo + 1048576);
  float* chunk0 = bias4 + 4096;

  const size_t fixedF = (size_t)5 * 131072 + 4194304   // states + WT
                      + 4194304                        // Wxt hi+lo (in floats)
                      + 1048576                        // Wot hi+lo (in floats)
                      + 4096;                          // bias4
  // per timestep: preC 2MB + xs hi/lo 0.5MB + hAll_hi 0.25MB = 720896 floats
  const size_t perTF = (size_t)128 * 4096 + 3 * 65536;
  const size_t availF = (ws_size / 4 > fixedF) ? (ws_size / 4 - fixedF) : 0;
  int Tc = (int)(availF / perTF);
  if (Tc > S_) Tc = S_;
  if (Tc < 1)  Tc = 1;

  float* preC   = chunk0;                               // [Tc][128][4096]
  u16*   xs_hi  = (u16*)(preC + (size_t)Tc * 524288);   // [Tc*128][1024]
  u16*   xs_lo  = xs_hi + (size_t)Tc * 131072;
  u16*   hAll_h = xs_lo + (size_t)Tc * 131072;          // [Tc*128][1024]

  // one-time prep
  k_zero<<<2560, 256, 0, stream>>>(hT0, 5 * 131072);
  k_wt<<<4096, 256, 0, stream>>>(Wf, Wi, Wc, Wo, WT);
  k_tr<<<dim3(16, 16, 5), 256, 0, stream>>>(Wf, Wi, Wc, Wo, Wout,
                                            Wxt_hi, Wxt_lo, Wot_hi, Wot_lo);
  k_bias<<<16, 256, 0, stream>>>(bfv, biv, bcv, bov, bias4);

  for (int t0 = 0; t0 < S_; t0 += Tc) {
    const int T = (S_ - t0 < Tc) ? (S_ - t0) : Tc;

    k_xsplit<<<dim3(64, T), 256, 0, stream>>>(x, xs_hi, xs_lo, t0);
    k_gemm_mfma<0><<<dim3(32, T), 256, 0, stream>>>(xs_hi, xs_lo, Wxt_hi, Wxt_lo,
                                                    bias4, preC, t0);
    for (int tl = 0; tl < T; ++tl) {
      const int tg = t0 + tl;
      const float* hin = (tg & 1) ? hT1 : hT0;
      float* hout      = (tg & 1) ? hT0 : hT1;
      k_step2<<<256, 512, 0, stream>>>(WT, preC, hin, hout,
                                       cb, nb, mb, hAll_h, tl);
    }
    k_gemm_mfma<1><<<dim3(8, T), 256, 0, stream>>>(hAll_h, hAll_h, Wot_hi, Wot_hi,
                                                   bout, out, t0);
  }

  k_tail<<<2048, 256, 0, stream>>>(hT0, cb, nb, mb, out + (size_t)B_ * S_ * H_);
}